// Round 8
// baseline (501.907 us; speedup 1.0000x reference)
//
#include <hip/hip_runtime.h>
#include <hip/hip_bf16.h>

// GCN forward: conv1(GEMM + sym-norm agg) -> BN -> PReLU -> conv2(GEMM + agg)
// N=100000, E=1600000, DIN=128, 2H=128, H=64. fp32 in/out.
//
// R8 changes vs R7 (425 us):
//  - bnstats_k was the top kernel at 70 us with 4.6% occupancy (512 waves of
//    64 threads, latency-starved serial row walk). Rewritten as a two-stage
//    reduction: 512 blocks x 256 threads (8 waves/CU), coalesced 4-rows-per-
//    iteration sweep, LDS reduce, fp32 partials to workspace (NO atomics);
//    bnfinal sums the 512 partials per feature. Predicted 70 -> ~7 us.
//  - Everything else unchanged (R7 = best measured: padded CSR, wave-per-node
//    aggs, prescaled bf16 h, bf16 z).

#define DIN 128
#define F1  128   // 2H
#define F2  64    // H
#define BN_EPS 1e-5f
#define NODE_BSHIFT 8          // 256 nodes per bucket
#define NODE_BMASK  255
#define CHUNK 8192             // edges per binpass block
#define BNBLK 512              // bnstats stage-1 blocks

__device__ __forceinline__ unsigned short f2bf(float f) {
    unsigned int u = __float_as_uint(f);
    u = u + 0x7fffu + ((u >> 16) & 1u);   // RNE
    return (unsigned short)(u >> 16);
}
__device__ __forceinline__ float bf_lo(unsigned int v) { return __uint_as_float(v << 16); }
__device__ __forceinline__ float bf_hi(unsigned int v) { return __uint_as_float(v & 0xffff0000u); }

// ---------------- graph build ----------------

__global__ __launch_bounds__(256) void hist_k(const int* __restrict__ dst,
                                              int* __restrict__ bucketcnt,
                                              int e, int nbuck) {
    __shared__ int lh[512];
    int t = threadIdx.x;
    for (int i = t; i < 512; i += 256) lh[i] = 0;
    __syncthreads();
    int base = blockIdx.x * CHUNK;
    int end = base + CHUNK; if (end > e) end = e;
    for (int i = base + t; i < end; i += 256)
        atomicAdd(&lh[dst[i] >> NODE_BSHIFT], 1);
    __syncthreads();
    for (int b = t; b < nbuck; b += 256) {
        int v = lh[b];
        if (v) atomicAdd(&bucketcnt[b], v);
    }
}

// exclusive scan of unpadded bucket counts -> pairs layout
__global__ __launch_bounds__(512) void bscan_k(const int* __restrict__ bucketcnt,
                                               int* __restrict__ bucketbase,
                                               int* __restrict__ bucketcur,
                                               int nbuck, int e) {
    __shared__ int s[512];
    int t = threadIdx.x;
    int orig = (t < nbuck) ? bucketcnt[t] : 0;
    s[t] = orig;
    __syncthreads();
    int run = orig;
    for (int ofs = 1; ofs < 512; ofs <<= 1) {
        int y = (t >= ofs) ? s[t - ofs] : 0;
        __syncthreads();
        run += y;
        s[t] = run;
        __syncthreads();
    }
    if (t < nbuck) {
        int excl = run - orig;
        bucketbase[t] = excl;
        bucketcur[t] = excl;
    }
    if (t == 0) bucketbase[nbuck] = e;
}

__global__ __launch_bounds__(256) void binpass_k(const int* __restrict__ src,
                                                 const int* __restrict__ dst,
                                                 int* __restrict__ bucketcur,
                                                 int2* __restrict__ pairs, int e) {
    __shared__ int lh[512], lbase[512], lrank[512];
    int t = threadIdx.x;
    for (int i = t; i < 512; i += 256) { lh[i] = 0; lrank[i] = 0; }
    __syncthreads();
    int base = blockIdx.x * CHUNK;
    int end = base + CHUNK; if (end > e) end = e;
    for (int i = base + t; i < end; i += 256)
        atomicAdd(&lh[dst[i] >> NODE_BSHIFT], 1);
    __syncthreads();
    for (int b = t; b < 512; b += 256) {
        int v = lh[b];
        lbase[b] = v ? atomicAdd(&bucketcur[b], v) : 0;
    }
    __syncthreads();
    for (int i = base + t; i < end; i += 256) {
        int sv = src[i], dv = dst[i];
        int b = dv >> NODE_BSHIFT;
        int r = atomicAdd(&lrank[b], 1);
        pairs[lbase[b] + r] = make_int2(sv, dv);
    }
}

// per-node degree + padded (mult-of-4) per-bucket totals
__global__ __launch_bounds__(256) void bdeg_k(const int2* __restrict__ pairs,
                                              const int* __restrict__ bucketbase,
                                              int* __restrict__ degi,
                                              int* __restrict__ pbucketcnt, int n) {
    __shared__ int lh[256], red[256];
    int b = blockIdx.x, t = threadIdx.x;
    int e0 = bucketbase[b], e1 = bucketbase[b + 1];
    lh[t] = 0;
    __syncthreads();
    for (int i = e0 + t; i < e1; i += 256)
        atomicAdd(&lh[pairs[i].y & NODE_BMASK], 1);
    __syncthreads();
    int node = (b << NODE_BSHIFT) + t;
    int deg = lh[t];
    int pdeg = (node < n) ? ((deg + 3) & ~3) : 0;
    if (node < n) degi[node] = deg;
    red[t] = pdeg;
    __syncthreads();
    for (int ofs = 128; ofs > 0; ofs >>= 1) {
        if (t < ofs) red[t] += red[t + ofs];
        __syncthreads();
    }
    if (t == 0) pbucketcnt[b] = red[0];
}

// exclusive scan of padded bucket totals -> srcsorted layout
__global__ __launch_bounds__(512) void pscan_k(const int* __restrict__ pbucketcnt,
                                               int* __restrict__ pbase,
                                               int* __restrict__ rowptr,
                                               int nbuck, int n) {
    __shared__ int s[512];
    int t = threadIdx.x;
    int orig = (t < nbuck) ? pbucketcnt[t] : 0;
    s[t] = orig;
    __syncthreads();
    int run = orig;
    for (int ofs = 1; ofs < 512; ofs <<= 1) {
        int y = (t >= ofs) ? s[t - ofs] : 0;
        __syncthreads();
        run += y;
        s[t] = run;
        __syncthreads();
    }
    if (t < nbuck) pbase[t] = run - orig;
    if (t == nbuck - 1) rowptr[n] = run;
}

// fine scatter into padded per-node regions; pad slots -> dummy node n
__global__ __launch_bounds__(256) void bucket2_k(const int2* __restrict__ pairs,
                                                 const int* __restrict__ bucketbase,
                                                 const int* __restrict__ degi,
                                                 const int* __restrict__ pbase,
                                                 float* __restrict__ dinv,
                                                 int* __restrict__ rowptr,
                                                 int* __restrict__ srcsorted, int n) {
    __shared__ int ps[256], loff[256], lrank[256];
    int b = blockIdx.x, t = threadIdx.x;
    int e0 = bucketbase[b], e1 = bucketbase[b + 1];
    int node = (b << NODE_BSHIFT) + t;
    int deg = (node < n) ? degi[node] : 0;
    int pdeg = (deg + 3) & ~3;
    lrank[t] = 0;
    ps[t] = pdeg;
    __syncthreads();
    int run = pdeg;
    for (int ofs = 1; ofs < 256; ofs <<= 1) {
        int y = (t >= ofs) ? ps[t - ofs] : 0;
        __syncthreads();
        run += y;
        ps[t] = run;
        __syncthreads();
    }
    int o = pbase[b] + (run - pdeg);
    loff[t] = o;
    if (node < n) {
        dinv[node] = rsqrtf((float)(deg + 1));   // +1 self-loop
        rowptr[node] = o;
    }
    __syncthreads();
    for (int i = e0 + t; i < e1; i += 256) {
        int2 p = pairs[i];
        int lo = p.y & NODE_BMASK;
        int r = atomicAdd(&lrank[lo], 1);
        srcsorted[loff[lo] + r] = p.x;
    }
    if (node < n)
        for (int i = deg; i < pdeg; i++) srcsorted[o + i] = n;   // pads -> zero row
}

// -------- GEMM1: h'(bf16) = dinv[row] * (x @ W1)  (N x 128 @ 128 x 128) --------

__global__ __launch_bounds__(256) void gemm1_k(const float* __restrict__ x,
                                               const float* __restrict__ W,
                                               const float* __restrict__ dinv,
                                               unsigned int* __restrict__ h, int n) {
    __shared__ float xs[64][DIN];
    int t = threadIdx.x;
    int row0 = blockIdx.x * 64;
    const float4* x4 = (const float4*)x;
#pragma unroll
    for (int i = 0; i < 8; i++) {
        int l = t + i * 256;
        int r = l >> 5;
        int c = l & 31;
        float4 v = make_float4(0.f, 0.f, 0.f, 0.f);
        if (row0 + r < n) v = x4[(size_t)(row0 + r) * 32 + c];
        *(float4*)&xs[r][c * 4] = v;
    }
    __syncthreads();
    int cg = t & 31;
    int r0 = (t >> 5) * 8;
    float acc[8][4];
#pragma unroll
    for (int r = 0; r < 8; r++)
#pragma unroll
        for (int c = 0; c < 4; c++) acc[r][c] = 0.f;
    const float4* W4 = (const float4*)W;
#pragma unroll 4
    for (int k = 0; k < DIN; k++) {
        float4 bv = W4[k * 32 + cg];
#pragma unroll
        for (int r = 0; r < 8; r++) {
            float a = xs[r0 + r][k];
            acc[r][0] = fmaf(a, bv.x, acc[r][0]);
            acc[r][1] = fmaf(a, bv.y, acc[r][1]);
            acc[r][2] = fmaf(a, bv.z, acc[r][2]);
            acc[r][3] = fmaf(a, bv.w, acc[r][3]);
        }
    }
    uint2* h2v = (uint2*)h;
#pragma unroll
    for (int r = 0; r < 8; r++) {
        int row = row0 + r0 + r;
        if (row < n) {
            float di = dinv[row];
            unsigned int p0 = (unsigned int)f2bf(di * acc[r][0]) | ((unsigned int)f2bf(di * acc[r][1]) << 16);
            unsigned int p1 = (unsigned int)f2bf(di * acc[r][2]) | ((unsigned int)f2bf(di * acc[r][3]) << 16);
            h2v[(size_t)row * 32 + cg] = make_uint2(p0, p1);
        }
    }
}

// ---- agg1: z(bf16) = di*(sum_s h'[s] + h'[nd]) + b1 ; one wave per node ----
// padded CSR: trip count exact multiple of 4, no tail.

__global__ __launch_bounds__(64) void agg1_k(const unsigned int* __restrict__ h,
                                             const float* __restrict__ dinv,
                                             const int* __restrict__ rowptr,
                                             const int* __restrict__ srcs,
                                             const float* __restrict__ b1,
                                             unsigned int* __restrict__ z, int n) {
    int nd = blockIdx.x;
    int f = threadIdx.x;               // uint (bf16 pair) index, 0..63
    int e = rowptr[nd], e1 = rowptr[nd + 1];
    float ax = 0.f, ay = 0.f;
    for (; e < e1; e += 4) {
        int s0 = srcs[e], s1 = srcs[e + 1], s2 = srcs[e + 2], s3 = srcs[e + 3];
        unsigned int v0 = h[(size_t)s0 * 64 + f];
        unsigned int v1 = h[(size_t)s1 * 64 + f];
        unsigned int v2 = h[(size_t)s2 * 64 + f];
        unsigned int v3 = h[(size_t)s3 * 64 + f];
        ax += bf_lo(v0); ay += bf_hi(v0);
        ax += bf_lo(v1); ay += bf_hi(v1);
        ax += bf_lo(v2); ay += bf_hi(v2);
        ax += bf_lo(v3); ay += bf_hi(v3);
    }
    unsigned int sv = h[(size_t)nd * 64 + f];   // self: h'[nd] = di*h[nd]
    ax += bf_lo(sv);
    ay += bf_hi(sv);
    float di = dinv[nd];
    float2 bb = ((const float2*)b1)[f];
    float zx = fmaf(ax, di, bb.x);
    float zy = fmaf(ay, di, bb.y);
    z[(size_t)nd * 64 + f] = (unsigned int)f2bf(zx) | ((unsigned int)f2bf(zy) << 16);
}

// ---------------- BatchNorm stats: two-stage, no atomics ----------------
// stage 1: 512 blocks x 256 threads; thread owns column t&63, row-group t>>6.
// partial layout per block (256 floats): [sx(64) | sy(64) | qx(64) | qy(64)]

__global__ __launch_bounds__(256) void bnstats_k(const unsigned int* __restrict__ z,
                                                 float* __restrict__ pstat, int n) {
    int t = threadIdx.x;
    int c = t & 63;
    int rg = t >> 6;                    // 0..3
    float sx = 0.f, sy = 0.f, qx = 0.f, qy = 0.f;
    for (int r = blockIdx.x * 4 + rg; r < n; r += gridDim.x * 4) {
        unsigned int v = z[(size_t)r * 64 + c];
        float a = bf_lo(v), b = bf_hi(v);
        sx += a; qx = fmaf(a, a, qx);
        sy += b; qy = fmaf(b, b, qy);
    }
    __shared__ float red[1024];
    red[t] = sx; red[256 + t] = sy; red[512 + t] = qx; red[768 + t] = qy;
    __syncthreads();
    if (t < 64) {
#pragma unroll
        for (int k = 0; k < 4; k++) {
            float s = red[k * 256 + t] + red[k * 256 + t + 64] +
                      red[k * 256 + t + 128] + red[k * 256 + t + 192];
            pstat[blockIdx.x * 256 + k * 64 + t] = s;
        }
    }
}

// stage 2: sum partials per feature, emit scale/shift.
// feature f: col = f>>1, lo/hi = f&1; sum at k=(f&1), qsum at k=2+(f&1).

__global__ __launch_bounds__(128) void bnfinal_k(const float* __restrict__ pstat,
                                                 const float* __restrict__ gamma,
                                                 const float* __restrict__ beta,
                                                 float* __restrict__ scale,
                                                 float* __restrict__ shift,
                                                 int n, int nblk) {
    int f = threadIdx.x;
    int off = (f & 1) * 64 + (f >> 1);
    float s = 0.f, q = 0.f;
    for (int b = 0; b < nblk; b++) {
        s += pstat[b * 256 + off];
        q += pstat[b * 256 + 128 + off];
    }
    float mean = s / n;
    float var = q / n - mean * mean;
    float sc = gamma[f] * rsqrtf(var + BN_EPS);
    scale[f] = sc;
    shift[f] = beta[f] - mean * sc;
}

// -- GEMM2: h2'(bf16) = dinv[row] * (prelu(bn(z)) @ W2)  (N x 128 @ 128 x 64) --

__global__ __launch_bounds__(256) void gemm2_k(const unsigned int* __restrict__ z,
                                               const float* __restrict__ W,
                                               const float* __restrict__ scale,
                                               const float* __restrict__ shift,
                                               const float* __restrict__ prelu_a,
                                               const float* __restrict__ dinv,
                                               unsigned int* __restrict__ h2, int n) {
    __shared__ float zs[64][F1];
    int t = threadIdx.x;
    int row0 = blockIdx.x * 64;
    float pa = prelu_a[0];
    const float2* sc2 = (const float2*)scale;
    const float2* sh2 = (const float2*)shift;
#pragma unroll
    for (int i = 0; i < 16; i++) {
        int l = t + i * 256;       // uint idx in 64x64-uint tile (4096)
        int r = l >> 6;
        int c = l & 63;
        unsigned int v = 0;
        if (row0 + r < n) v = z[(size_t)(row0 + r) * 64 + c];
        float2 sc = sc2[c], sh = sh2[c];
        float a = fmaf(bf_lo(v), sc.x, sh.x); a = a >= 0.f ? a : pa * a;
        float b = fmaf(bf_hi(v), sc.y, sh.y); b = b >= 0.f ? b : pa * b;
        zs[r][2 * c] = a;
        zs[r][2 * c + 1] = b;
    }
    __syncthreads();
    int cg = t & 15;
    int r0 = (t >> 4) * 4;
    float acc[4][4];
#pragma unroll
    for (int r = 0; r < 4; r++)
#pragma unroll
        for (int c = 0; c < 4; c++) acc[r][c] = 0.f;
    const float4* W4 = (const float4*)W;
#pragma unroll 4
    for (int k = 0; k < F1; k++) {
        float4 bv = W4[k * 16 + cg];
#pragma unroll
        for (int r = 0; r < 4; r++) {
            float a = zs[r0 + r][k];
            acc[r][0] = fmaf(a, bv.x, acc[r][0]);
            acc[r][1] = fmaf(a, bv.y, acc[r][1]);
            acc[r][2] = fmaf(a, bv.z, acc[r][2]);
            acc[r][3] = fmaf(a, bv.w, acc[r][3]);
        }
    }
    uint2* o2 = (uint2*)h2;
#pragma unroll
    for (int r = 0; r < 4; r++) {
        int row = row0 + r0 + r;
        if (row < n) {
            float di = dinv[row];
            unsigned int p0 = (unsigned int)f2bf(di * acc[r][0]) | ((unsigned int)f2bf(di * acc[r][1]) << 16);
            unsigned int p1 = (unsigned int)f2bf(di * acc[r][2]) | ((unsigned int)f2bf(di * acc[r][3]) << 16);
            o2[(size_t)row * 16 + cg] = make_uint2(p0, p1);
        }
    }
}

// ---- agg2: out(fp32) = di*(sum h2'[s] + h2'[nd]) + b2 ; 2 half-wave nodes/block ----

__global__ __launch_bounds__(64) void agg2_k(const unsigned int* __restrict__ h2,
                                             const float* __restrict__ dinv,
                                             const int* __restrict__ rowptr,
                                             const int* __restrict__ srcs,
                                             const float* __restrict__ b2,
                                             float2* __restrict__ out, int n) {
    int half = threadIdx.x >> 5;       // 0..1
    int f = threadIdx.x & 31;          // uint idx in 32-uint row
    int nd = blockIdx.x * 2 + half;
    if (nd >= n) return;
    int e = rowptr[nd], e1 = rowptr[nd + 1];
    float ax = 0.f, ay = 0.f;
    for (; e < e1; e += 4) {
        int s0 = srcs[e], s1 = srcs[e + 1], s2 = srcs[e + 2], s3 = srcs[e + 3];
        unsigned int v0 = h2[(size_t)s0 * 32 + f];
        unsigned int v1 = h2[(size_t)s1 * 32 + f];
        unsigned int v2 = h2[(size_t)s2 * 32 + f];
        unsigned int v3 = h2[(size_t)s3 * 32 + f];
        ax += bf_lo(v0); ay += bf_hi(v0);
        ax += bf_lo(v1); ay += bf_hi(v1);
        ax += bf_lo(v2); ay += bf_hi(v2);
        ax += bf_lo(v3); ay += bf_hi(v3);
    }
    unsigned int sv = h2[(size_t)nd * 32 + f];
    ax += bf_lo(sv);
    ay += bf_hi(sv);
    float di = dinv[nd];
    float2 bb = ((const float2*)b2)[f];
    float2 o;
    o.x = fmaf(ax, di, bb.x);
    o.y = fmaf(ay, di, bb.y);
    out[(size_t)nd * 32 + f] = o;
}

// ---------------- launch ----------------

extern "C" void kernel_launch(void* const* d_in, const int* in_sizes, int n_in,
                              void* d_out, int out_size, void* d_ws, size_t ws_size,
                              hipStream_t stream) {
    const float* x       = (const float*)d_in[0];
    const int*   ei      = (const int*)d_in[1];
    const float* W1      = (const float*)d_in[2];
    const float* b1      = (const float*)d_in[3];
    const float* W2      = (const float*)d_in[4];
    const float* b2      = (const float*)d_in[5];
    const float* gamma   = (const float*)d_in[6];
    const float* beta    = (const float*)d_in[7];
    const float* prelu_a = (const float*)d_in[8];

    const int N = in_sizes[0] / DIN;
    const int E = in_sizes[1] / 2;
    const int* src = ei;
    const int* dst = ei + E;
    const int NBUCK = (N + NODE_BMASK) >> NODE_BSHIFT;  // 391

    char* p = (char*)d_ws;
    size_t off = 0;
    auto take = [&](size_t bytes) -> char* {
        char* r = p + off;
        off = (off + bytes + 255) & ~(size_t)255;
        return r;
    };
    int*          bucketcnt  = (int*)take(512 * 4);
    int*          bucketbase = (int*)take(513 * 4);
    int*          bucketcur  = (int*)take(512 * 4);
    int*          pbucketcnt = (int*)take(512 * 4);
    int*          pbase      = (int*)take(513 * 4);
    int*          degi       = (int*)take((size_t)N * 4);
    float*        dinv       = (float*)take((size_t)N * 4);
    int*          rowptr     = (int*)take((size_t)(N + 1) * 4);
    int*          srcsorted  = (int*)take((size_t)(E + 4 * N) * 4);
    int2*         pairs      = (int2*)take((size_t)E * 8);
    float*        pstat      = (float*)take((size_t)BNBLK * 256 * 4);
    float*        scale      = (float*)take(F1 * 4);
    float*        shift      = (float*)take(F1 * 4);
    unsigned int* h          = (unsigned int*)take((size_t)(N + 1) * 64 * 4);  // bf16 h' + zero row
    unsigned int* z          = (unsigned int*)take((size_t)N * 64 * 4);        // bf16 z
    unsigned int* h2         = h;  // h dead after agg1; bf16 h2' ((N+1)*32 uints fits)
    float*        out        = (float*)d_out;

    hipMemsetAsync(bucketcnt, 0, 512 * 4, stream);

    const int eb = (E + CHUNK - 1) / CHUNK;

    hist_k<<<eb, 256, 0, stream>>>(dst, bucketcnt, E, NBUCK);
    bscan_k<<<1, 512, 0, stream>>>(bucketcnt, bucketbase, bucketcur, NBUCK, E);
    binpass_k<<<eb, 256, 0, stream>>>(src, dst, bucketcur, pairs, E);
    bdeg_k<<<NBUCK, 256, 0, stream>>>(pairs, bucketbase, degi, pbucketcnt, N);
    pscan_k<<<1, 512, 0, stream>>>(pbucketcnt, pbase, rowptr, NBUCK, N);
    bucket2_k<<<NBUCK, 256, 0, stream>>>(pairs, bucketbase, degi, pbase, dinv, rowptr, srcsorted, N);

    gemm1_k<<<(N + 63) / 64, 256, 0, stream>>>(x, W1, dinv, h, N);
    hipMemsetAsync(h + (size_t)N * 64, 0, 64 * 4, stream);   // zero dummy row N

    agg1_k<<<N, 64, 0, stream>>>(h, dinv, rowptr, srcsorted, b1, z, N);
    bnstats_k<<<BNBLK, 256, 0, stream>>>(z, pstat, N);
    bnfinal_k<<<1, 128, 0, stream>>>(pstat, gamma, beta, scale, shift, N, BNBLK);

    gemm2_k<<<(N + 63) / 64, 256, 0, stream>>>(z, W2, scale, shift, prelu_a, dinv, h2, N);
    hipMemsetAsync(h2 + (size_t)N * 32, 0, 32 * 4, stream);  // zero dummy row N (h2 layout)

    agg2_k<<<(N + 1) / 2, 64, 0, stream>>>(h2, dinv, rowptr, srcsorted, b2, (float2*)out, N);
}